// Round 11
// baseline (168.999 us; speedup 1.0000x reference)
//
#include <hip/hip_runtime.h>
#include <hip/hip_bf16.h>
#include <stdint.h>
#include <math.h>

using bf16x8 = __attribute__((ext_vector_type(8))) short;
using bf16x4 = __attribute__((ext_vector_type(4))) short;
using f32x4  = __attribute__((ext_vector_type(4))) float;

#define DEV static __device__ __forceinline__

// SESSION LEDGER:
//  - r6/7 bisect: v_cvt_pk_bf16_f32 INLINE ASM => NaN. BANNED.
//    __float22bfloat162_rn compiler path => green (r9). Use packbf.
//  - r8: splitting the Q axis (64-row blocks) REGRESSED: 2x K/V staging.
//    Split KV instead (this round): staging/LDS/VALU totals unchanged.
//  - r10: BK=64 swizzled-glds GEMM green, bit-identical. r5 NaN attributed to
//    cvtpk-asm context/flake. If an unexplained NaN recurs: revert GEMM to
//    BK=32 FIRST.

DEV float bf2f(short s) {
  union { unsigned u; float f; } v; v.u = ((unsigned)(unsigned short)s) << 16; return v.f;
}
DEV short f2bf(float f) {
  union { float ff; unsigned u; } v; v.ff = f;
  unsigned r = v.u + 0x7fffu + ((v.u >> 16) & 1u);
  return (short)(r >> 16);
}
DEV unsigned packbf(float a, float b) {  // lo16 = RNE(a), hi16 = RNE(b)
  __hip_bfloat162 h = __float22bfloat162_rn(make_float2(a, b));
  union { __hip_bfloat162 h2; unsigned u; } v; v.h2 = h; return v.u;
}

DEV f32x4 mfma16x16x32(bf16x8 a, bf16x8 b, f32x4 c) {
  return __builtin_amdgcn_mfma_f32_16x16x32_bf16(a, b, c, 0, 0, 0);
}

DEV void glds16(const void* g, void* l) {
  __builtin_amdgcn_global_load_lds(
      (__attribute__((address_space(1))) void*)(uintptr_t)(g),
      (__attribute__((address_space(3))) void*)(l), 16, 0, 0);
}

#define B_   2
#define N_   2048
#define DIM_ 1024
#define H_   16
#define DH_  64
#define BH_  (B_ * H_)
#define BN_  (B_ * N_)
#define OPART_HALF_STRIDE ((size_t)BH_ * N_ * DH_)   // 4194304 shorts = 8 MiB
#define ROWS_TOT (BH_ * N_)                          // 65536

// ---------------------------------------------------------------------------
// 1) cos/sin table: cs[(n*32+j)*2] = cos(n * 10000^(-2j/64)), +1 = sin
// ---------------------------------------------------------------------------
__global__ void cs_kernel(float* __restrict__ cs) {
  int tid = blockIdx.x * blockDim.x + threadIdx.x;   // 65536 = 2048 * 32
  int n = tid >> 5, j = tid & 31;
  float inv = powf(10000.0f, -(float)(2 * j) / 64.0f);
  float ang = (float)n * inv;
  cs[2 * tid]     = cosf(ang);
  cs[2 * tid + 1] = sinf(ang);
}

// ---------------------------------------------------------------------------
// 2) fp32 -> bf16 elementwise (for x)
// ---------------------------------------------------------------------------
__global__ __launch_bounds__(256) void conv_kernel(const float* __restrict__ src,
                                                   short* __restrict__ dst) {
  int i = (blockIdx.x * 256 + threadIdx.x) * 8;
  float4 a = *(const float4*)(src + i);
  float4 b = *(const float4*)(src + i + 4);
  bf16x8 o;
  o[0] = f2bf(a.x); o[1] = f2bf(a.y); o[2] = f2bf(a.z); o[3] = f2bf(a.w);
  o[4] = f2bf(b.x); o[5] = f2bf(b.y); o[6] = f2bf(b.z); o[7] = f2bf(b.w);
  *(bf16x8*)(dst + i) = o;
}

// ---------------------------------------------------------------------------
// 3) transpose fp32 [R][C] -> bf16 [C][R]  (64x64 LDS tiles)
// ---------------------------------------------------------------------------
__global__ __launch_bounds__(256) void transw_kernel(const float* __restrict__ src,
                                                     short* __restrict__ dst,
                                                     int R, int C) {
  __shared__ unsigned short lds[64 * 65];
  const int t = threadIdx.x;
  const int cb = blockIdx.x * 64, rb = blockIdx.y * 64;
  #pragma unroll
  for (int pass = 0; pass < 4; ++pass) {
    int r  = pass * 16 + (t >> 4);
    int cc = (t & 15) * 4;
    float4 v = *(const float4*)(src + (size_t)(rb + r) * C + cb + cc);
    lds[(cc + 0) * 65 + r] = (unsigned short)f2bf(v.x);
    lds[(cc + 1) * 65 + r] = (unsigned short)f2bf(v.y);
    lds[(cc + 2) * 65 + r] = (unsigned short)f2bf(v.z);
    lds[(cc + 3) * 65 + r] = (unsigned short)f2bf(v.w);
  }
  __syncthreads();
  const int cl = t >> 2, chunk = t & 3;
  bf16x8 o0, o1;
  #pragma unroll
  for (int j = 0; j < 8; ++j) {
    o0[j] = (short)lds[cl * 65 + chunk * 16 + j];
    o1[j] = (short)lds[cl * 65 + chunk * 16 + 8 + j];
  }
  size_t off = (size_t)(cb + cl) * R + rb + chunk * 16;
  *(bf16x8*)(dst + off)     = o0;
  *(bf16x8*)(dst + off + 8) = o1;
}

// ---------------------------------------------------------------------------
// 4) GEMM: C[M][N] = A[M][K] (bf16, row-major) @ BT[N][K]^T (bf16)
//    128x128 tile, BK=64, chunk-XOR swizzled glds source (r10-proven).
// ---------------------------------------------------------------------------
template <bool OUTBF16>
__global__ __launch_bounds__(256) void gemm_bt_kernel(const short* __restrict__ A,
                                                      const short* __restrict__ BT,
                                                      void* __restrict__ Cout,
                                                      int M, int N, int K, int gx) {
  __shared__ short As[128 * 64];
  __shared__ short Bs[128 * 64];
  const int nwg = gridDim.x;
  const int bid = blockIdx.x;
  const int swz = (bid & 7) * (nwg >> 3) + (bid >> 3);  // bijective: nwg%8==0
  const int bx = swz % gx, by = swz / gx;
  const int t = threadIdx.x;
  const int lane = t & 63, w = t >> 6;
  const int c = lane & 15, g = lane >> 4;
  const int wm = w >> 1, wn = w & 1;
  const int mbase = by * 128, nbase = bx * 128;
  const short* Ab = A + (size_t)mbase * K;
  const short* Bb = BT + (size_t)nbase * K;
  f32x4 acc[4][4] = {};
  for (int kb2 = 0; kb2 < K; kb2 += 64) {
    #pragma unroll
    for (int i = 0; i < 4; ++i) {
      const int idx = i * 256 + t;             // 0..1023 chunk id
      const int row = idx >> 3, p = idx & 7;
      const int gc = ((p ^ (row & 7)) << 3);   // source chunk pre-swizzle
      glds16(Ab + (size_t)row * K + kb2 + gc, As + idx * 8);
      glds16(Bb + (size_t)row * K + kb2 + gc, Bs + idx * 8);
    }
    __syncthreads();
    bf16x8 af[4][2], bfr[4][2];
    #pragma unroll
    for (int mi = 0; mi < 4; ++mi) {
      const int r = wm * 64 + mi * 16 + c;
      #pragma unroll
      for (int kk = 0; kk < 2; ++kk)
        af[mi][kk] = *(const bf16x8*)&As[r * 64 + (((kk * 4 + g) ^ (r & 7)) << 3)];
    }
    #pragma unroll
    for (int ni = 0; ni < 4; ++ni) {
      const int r = wn * 64 + ni * 16 + c;
      #pragma unroll
      for (int kk = 0; kk < 2; ++kk)
        bfr[ni][kk] = *(const bf16x8*)&Bs[r * 64 + (((kk * 4 + g) ^ (r & 7)) << 3)];
    }
    #pragma unroll
    for (int kk = 0; kk < 2; ++kk)
      #pragma unroll
      for (int mi = 0; mi < 4; ++mi)
        #pragma unroll
        for (int ni = 0; ni < 4; ++ni)
          acc[mi][ni] = mfma16x16x32(af[mi][kk], bfr[ni][kk], acc[mi][ni]);
    __syncthreads();
  }
  #pragma unroll
  for (int mi = 0; mi < 4; ++mi) {
    const int row = mbase + wm * 64 + mi * 16 + g * 4;
    #pragma unroll
    for (int ni = 0; ni < 4; ++ni) {
      const int col = nbase + wn * 64 + ni * 16 + c;
      #pragma unroll
      for (int r = 0; r < 4; ++r) {
        if constexpr (OUTBF16)
          ((short*)Cout)[(size_t)(row + r) * N + col] = f2bf(acc[mi][ni][r]);
        else
          ((float*)Cout)[(size_t)(row + r) * N + col] = acc[mi][ni][r];
      }
    }
  }
}

// ---------------------------------------------------------------------------
// 5) RoPE on q,k: qkv bf16 [4096][3072] cols 0..2047 -> qb/kb [BH][N][64] bf16
//    q additionally scaled by 0.125 (EXACT pow2, folds softmax scale)
// ---------------------------------------------------------------------------
__global__ __launch_bounds__(256) void ropeqk_kernel(const short* __restrict__ qkv,
                                                     const float* __restrict__ cs,
                                                     short* __restrict__ qb,
                                                     short* __restrict__ kb) {
  int tid = blockIdx.x * 256 + threadIdx.x;  // 2097152 threads, 4 elems each
  int e   = tid * 4;
  int bn  = e >> 11;
  int col = e & 2047;
  int i3  = col >> 10;
  int h   = (col >> 6) & 15;
  int d   = col & 63;
  int n   = bn & (N_ - 1);
  int b   = bn >> 11;
  bf16x4 v = *(const bf16x4*)(qkv + (size_t)bn * 3072 + col);
  float4 t4 = *(const float4*)(cs + ((size_t)n * 32 + (d >> 1)) * 2); // c0,s0,c1,s1
  float x0 = bf2f(v[0]), x1 = bf2f(v[1]), x2 = bf2f(v[2]), x3 = bf2f(v[3]);
  float r0 = x0 * t4.x - x1 * t4.y;
  float r1 = x0 * t4.y + x1 * t4.x;
  float r2 = x2 * t4.z - x3 * t4.w;
  float r3 = x2 * t4.w + x3 * t4.z;
  float sc = (i3 == 0) ? 0.125f : 1.0f;
  bf16x4 ov;
  ov[0] = f2bf(r0 * sc); ov[1] = f2bf(r1 * sc);
  ov[2] = f2bf(r2 * sc); ov[3] = f2bf(r3 * sc);
  short* dst = (i3 == 0) ? qb : kb;
  *(bf16x4*)(dst + (((size_t)(b * H_ + h) * N_ + n) * DH_ + d)) = ov;
}

// ---------------------------------------------------------------------------
// 6) V transpose: qkv cols 2048..3071 -> vT [BH][64][N] bf16
// ---------------------------------------------------------------------------
__global__ __launch_bounds__(256) void transv_kernel(const short* __restrict__ qkv,
                                                     short* __restrict__ vT) {
  __shared__ unsigned short lds[64 * 65];
  const int t = threadIdx.x;
  const int ntile = blockIdx.x;  // 0..31
  const int bh = blockIdx.y;     // 0..31
  const int b = bh >> 4, h = bh & 15;
  #pragma unroll
  for (int pass = 0; pass < 2; ++pass) {
    int rloc = pass * 32 + (t >> 3);
    int dc = t & 7;
    const short* src = qkv + (size_t)(b * N_ + ntile * 64 + rloc) * 3072 + 2048 + h * 64 + dc * 8;
    bf16x8 v = *(const bf16x8*)src;
    #pragma unroll
    for (int j = 0; j < 8; ++j) lds[(dc * 8 + j) * 65 + rloc] = (unsigned short)v[j];
  }
  __syncthreads();
  const int dl = t >> 2, chunk = t & 3;
  bf16x8 o0, o1;
  #pragma unroll
  for (int j = 0; j < 8; ++j) {
    o0[j] = (short)lds[dl * 65 + chunk * 16 + j];
    o1[j] = (short)lds[dl * 65 + chunk * 16 + 8 + j];
  }
  short* dst = vT + ((size_t)bh * 64 + dl) * N_ + ntile * 64 + chunk * 16;
  *(bf16x8*)dst       = o0;
  *(bf16x8*)(dst + 8) = o1;
}

// ---------------------------------------------------------------------------
// 7) Flash attention, SPLIT-KV (2 halves of 16 tiles each). Per-tile compute
//    bit-identical to r10 green form. Each block handles one (bh, 128-q, half)
//    triple -> 1024 blocks = 4/CU = 4 waves/SIMD; staging totals UNCHANGED
//    (each block stages only its own kv half). Outputs per-half normalized
//    o (bf16) + (M, L) partials; combine_kernel merges exactly.
// ---------------------------------------------------------------------------
__global__ __launch_bounds__(256) void attn_kernel(const short* __restrict__ qb,
                                                   const short* __restrict__ kb,
                                                   const short* __restrict__ vT,
                                                   short* __restrict__ opart,
                                                   float2* __restrict__ mlpart) {
  __shared__ short Kt[2][4096];   // 8 KB per buf: [row 0..63][chunk 0..7][8]
  __shared__ short Vt[2][4096];
  const int t = threadIdx.x;
  const int lane = t & 63, w = t >> 6;
  const int c = lane & 15, g = lane >> 4;
  const int bid = blockIdx.x;               // 1024 blocks, 1D
  const int xcd = bid & 7, slot = bid >> 3; // slot 0..127
  const int bh = xcd + ((slot >> 5) << 3);  // 32 blocks of bh share an XCD
  const int half = (slot >> 4) & 1;
  const int xb = slot & 15;
  const int qbase = xb * 128 + w * 32;
  const short* kbase = kb + (size_t)bh * N_ * DH_;
  const short* vbase = vT + (size_t)bh * DH_ * N_;
  const int it0 = half * 16;                // kv tiles [it0, it0+16)

  // staging map (per thread, 2 chunks per array): ch = j*256+t
  const int s_row0 = t >> 3,          s_p0 = t & 7;
  const int s_row1 = (256 + t) >> 3,  s_p1 = t & 7;   // rows 32..63
  const int s_dst0 = s_row0 * 64 + ((s_p0 ^ (s_row0 & 7)) << 3);
  const int s_dst1 = s_row1 * 64 + ((s_p1 ^ (s_row1 & 7)) << 3);

  // Q fragments held in registers for the whole kv loop; q pre-scaled 1/8
  bf16x8 qlo[2], qhi[2];
  #pragma unroll
  for (int qf = 0; qf < 2; ++qf) {
    const short* qp = qb + ((size_t)bh * N_ + qbase + qf * 16 + c) * DH_;
    qlo[qf] = *(const bf16x8*)(qp + g * 8);
    qhi[qf] = *(const bf16x8*)(qp + 32 + g * 8);
  }

  float M[2] = {-INFINITY, -INFINITY};
  float L[2] = {0.f, 0.f};
  f32x4 o[4][2] = {};
  bf16x8 kr0, kr1, vr0, vr1;

  // prologue: load tile it0 -> regs, write buf 0, barrier
  kr0 = *(const bf16x8*)(kbase + (size_t)(it0 * 64 + s_row0) * DH_ + s_p0 * 8);
  kr1 = *(const bf16x8*)(kbase + (size_t)(it0 * 64 + s_row1) * DH_ + s_p1 * 8);
  vr0 = *(const bf16x8*)(vbase + (size_t)s_row0 * N_ + it0 * 64 + s_p0 * 8);
  vr1 = *(const bf16x8*)(vbase + (size_t)s_row1 * N_ + it0 * 64 + s_p1 * 8);
  *(bf16x8*)(&Kt[0][s_dst0]) = kr0;
  *(bf16x8*)(&Kt[0][s_dst1]) = kr1;
  *(bf16x8*)(&Vt[0][s_dst0]) = vr0;
  *(bf16x8*)(&Vt[0][s_dst1]) = vr1;
  __syncthreads();

  for (int i = 0; i < 16; ++i) {
    const int cur = i & 1;
    const int pf_valid = (i + 1 < 16);
    if (pf_valid) {  // issue next-tile loads BEFORE compute (overlap)
      const int kv = (it0 + i + 1) * 64;
      kr0 = *(const bf16x8*)(kbase + (size_t)(kv + s_row0) * DH_ + s_p0 * 8);
      kr1 = *(const bf16x8*)(kbase + (size_t)(kv + s_row1) * DH_ + s_p1 * 8);
      vr0 = *(const bf16x8*)(vbase + (size_t)s_row0 * N_ + kv + s_p0 * 8);
      vr1 = *(const bf16x8*)(vbase + (size_t)s_row1 * N_ + kv + s_p1 * 8);
    }
    // --- QK^T ---
    f32x4 s[4][2] = {};
    __builtin_amdgcn_s_setprio(1);
    #pragma unroll
    for (int jt = 0; jt < 4; ++jt) {
      const int r_ = jt * 16 + c;
      const short* kt = &Kt[cur][r_ * 64];
      bf16x8 k0 = *(const bf16x8*)(kt + ((g ^ (r_ & 7)) << 3));
      bf16x8 k1 = *(const bf16x8*)(kt + (((g + 4) ^ (r_ & 7)) << 3));
      #pragma unroll
      for (int qf = 0; qf < 2; ++qf) {
        s[jt][qf] = mfma16x16x32(k0, qlo[qf], s[jt][qf]);
        s[jt][qf] = mfma16x16x32(k1, qhi[qf], s[jt][qf]);
      }
    }
    __builtin_amdgcn_s_setprio(0);
    // --- online softmax (exact every-tile rescale) + packbf P pack ---
    bf16x8 pf[2][2];
    #pragma unroll
    for (int qf = 0; qf < 2; ++qf) {
      float m0 = fmaxf(fmaxf(s[0][qf][0], s[0][qf][1]), s[0][qf][2]);
      float m1 = fmaxf(fmaxf(s[0][qf][3], s[1][qf][0]), s[1][qf][1]);
      float m2 = fmaxf(fmaxf(s[1][qf][2], s[1][qf][3]), s[2][qf][0]);
      float m3 = fmaxf(fmaxf(s[2][qf][1], s[2][qf][2]), s[2][qf][3]);
      float m4 = fmaxf(fmaxf(s[3][qf][0], s[3][qf][1]), s[3][qf][2]);
      float mx = fmaxf(fmaxf(fmaxf(m0, m1), fmaxf(m2, m3)),
                       fmaxf(m4, s[3][qf][3]));
      mx = fmaxf(mx, __shfl_xor(mx, 16));
      mx = fmaxf(mx, __shfl_xor(mx, 32));
      const float mnew = fmaxf(M[qf], mx);
      const float corr = __expf(M[qf] - mnew);  // exp(-inf)=0 first tile
      float rs = 0.f;
      #pragma unroll
      for (int jt = 0; jt < 4; ++jt)
        #pragma unroll
        for (int r = 0; r < 4; ++r) {
          s[jt][qf][r] = __expf(s[jt][qf][r] - mnew);
          rs += s[jt][qf][r];
        }
      rs += __shfl_xor(rs, 16);
      rs += __shfl_xor(rs, 32);
      L[qf] = L[qf] * corr + rs;
      M[qf] = mnew;
      #pragma unroll
      for (int dt = 0; dt < 4; ++dt) o[dt][qf] *= corr;
      union { unsigned u[4]; bf16x8 v; } P0, P1;
      P0.u[0] = packbf(s[0][qf][0], s[0][qf][1]);
      P0.u[1] = packbf(s[0][qf][2], s[0][qf][3]);
      P0.u[2] = packbf(s[1][qf][0], s[1][qf][1]);
      P0.u[3] = packbf(s[1][qf][2], s[1][qf][3]);
      P1.u[0] = packbf(s[2][qf][0], s[2][qf][1]);
      P1.u[1] = packbf(s[2][qf][2], s[2][qf][3]);
      P1.u[2] = packbf(s[3][qf][0], s[3][qf][1]);
      P1.u[3] = packbf(s[3][qf][2], s[3][qf][3]);
      pf[qf][0] = P0.v;
      pf[qf][1] = P1.v;
    }
    // --- PV ---
    __builtin_amdgcn_s_setprio(1);
    #pragma unroll
    for (int dt = 0; dt < 4; ++dt) {
      const int d = dt * 16 + c;
      const short* vt = &Vt[cur][d * 64];
      const int dx = d & 7;
      #pragma unroll
      for (int kf = 0; kf < 2; ++kf) {
        const int e0 = kf * 32 + g * 4;
        const int e1 = e0 + 16;
        bf16x4 a0 = *(const bf16x4*)(vt + ((((e0 >> 3) ^ dx) << 3) | (e0 & 7)));
        bf16x4 a1 = *(const bf16x4*)(vt + ((((e1 >> 3) ^ dx) << 3) | (e1 & 7)));
        bf16x8 vf = __builtin_shufflevector(a0, a1, 0, 1, 2, 3, 4, 5, 6, 7);
        o[dt][0] = mfma16x16x32(vf, pf[0][kf], o[dt][0]);
        o[dt][1] = mfma16x16x32(vf, pf[1][kf], o[dt][1]);
      }
    }
    __builtin_amdgcn_s_setprio(0);
    // --- write-late: store prefetched regs into the idle buffer ---
    if (pf_valid) {
      *(bf16x8*)(&Kt[cur ^ 1][s_dst0]) = kr0;
      *(bf16x8*)(&Kt[cur ^ 1][s_dst1]) = kr1;
      *(bf16x8*)(&Vt[cur ^ 1][s_dst0]) = vr0;
      *(bf16x8*)(&Vt[cur ^ 1][s_dst1]) = vr1;
    }
    __syncthreads();
  }

  // epilogue: per-half normalized o (bf16) + (M, L) partials
  #pragma unroll
  for (int qf = 0; qf < 2; ++qf) {
    const int row = bh * N_ + qbase + qf * 16 + c;
    const float inv = 1.0f / L[qf];
    short* op = opart + (size_t)half * OPART_HALF_STRIDE + (size_t)row * DH_;
    #pragma unroll
    for (int dt = 0; dt < 4; ++dt) {
      bf16x4 ov;
      #pragma unroll
      for (int r = 0; r < 4; ++r) ov[r] = f2bf(o[dt][qf][r] * inv);
      *(bf16x4*)(op + dt * 16 + g * 4) = ov;
    }
    if (g == 0) mlpart[half * ROWS_TOT + row] = make_float2(M[qf], L[qf]);
  }
}

// ---------------------------------------------------------------------------
// 8) Combine: out = (w0*o0 + w1*o1) / (w0+w1), w_h = exp(M_h - m*) * L_h.
//    Exact online-softmax merge in f32. Also scatters to [b][q][h][d] layout.
// ---------------------------------------------------------------------------
__global__ __launch_bounds__(256) void combine_kernel(const short* __restrict__ opart,
                                                      const float2* __restrict__ mlpart,
                                                      short* __restrict__ attn_out) {
  int tid = blockIdx.x * 256 + threadIdx.x;   // 131072 threads
  int row = tid >> 1;                          // 0..65535 = bh*2048 + q
  int dh  = (tid & 1) * 32;
  float2 ml0 = mlpart[row];
  float2 ml1 = mlpart[ROWS_TOT + row];
  float m  = fmaxf(ml0.x, ml1.x);
  float w0 = __expf(ml0.x - m) * ml0.y;
  float w1 = __expf(ml1.x - m) * ml1.y;
  float inv = 1.0f / (w0 + w1);
  w0 *= inv; w1 *= inv;
  const short* p0 = opart + (size_t)row * DH_ + dh;
  const short* p1 = p0 + OPART_HALF_STRIDE;
  const int bh = row >> 11, q = row & 2047, b = bh >> 4, h = bh & 15;
  short* dst = attn_out + (((size_t)(b * N_ + q) * H_ + h) * DH_) + dh;
  #pragma unroll
  for (int j = 0; j < 4; ++j) {
    bf16x8 v0 = *(const bf16x8*)(p0 + j * 8);
    bf16x8 v1 = *(const bf16x8*)(p1 + j * 8);
    bf16x8 ov;
    #pragma unroll
    for (int k = 0; k < 8; ++k)
      ov[k] = f2bf(w0 * bf2f(v0[k]) + w1 * bf2f(v1[k]));
    *(bf16x8*)(dst + j * 8) = ov;
  }
}

// ---------------------------------------------------------------------------
extern "C" void kernel_launch(void* const* d_in, const int* in_sizes, int n_in,
                              void* d_out, int out_size, void* d_ws, size_t ws_size,
                              hipStream_t stream) {
  const float* x    = (const float*)d_in[0];
  const float* Wqkv = (const float*)d_in[1];
  const float* Wout = (const float*)d_in[2];
  char* ws = (char*)d_ws;
  // workspace layout (MiB offsets)
  short* xb    = (short*)(ws);                        // 8 MiB  [4096][1024]
  short* WqkvT = (short*)(ws + ((size_t)8 << 20));    // 6 MiB  [3072][1024]
  short* WoutT = (short*)(ws + ((size_t)14 << 20));   // 2 MiB  [1024][1024]
  short* qkv   = (short*)(ws + ((size_t)16 << 20));   // 24 MiB [4096][3072] (dead after transv)
  short* opart = (short*)(ws + ((size_t)16 << 20));   // 16 MiB [2][32][2048][64] bf16 (aliases qkv)
  float2* mlpart = (float2*)(ws + ((size_t)33 << 20));// 1 MiB  [2][65536] (aliases qkv tail)
  short* qb    = (short*)(ws + ((size_t)40 << 20));   // 8 MiB  [32][2048][64]
  short* kb    = (short*)(ws + ((size_t)48 << 20));   // 8 MiB
  short* vT    = (short*)(ws + ((size_t)56 << 20));   // 8 MiB  [32][64][2048]
  short* attn  = (short*)(ws + ((size_t)64 << 20));   // 8 MiB  [4096][1024]
  float* cs    = (float*)(ws + ((size_t)72 << 20));   // 0.5 MiB [2048][32][2]

  cs_kernel<<<dim3(256), 256, 0, stream>>>(cs);
  conv_kernel<<<dim3(2048), 256, 0, stream>>>(x, xb);                       // x -> bf16
  transw_kernel<<<dim3(48, 16), 256, 0, stream>>>(Wqkv, WqkvT, 1024, 3072); // Wqkv^T
  transw_kernel<<<dim3(16, 16), 256, 0, stream>>>(Wout, WoutT, 1024, 1024); // Wout^T
  gemm_bt_kernel<true><<<dim3(768), 256, 0, stream>>>(xb, WqkvT, (void*)qkv, 4096, 3072, 1024, 24);
  ropeqk_kernel<<<dim3(8192), 256, 0, stream>>>(qkv, cs, qb, kb);
  transv_kernel<<<dim3(32, 32), 256, 0, stream>>>(qkv, vT);
  attn_kernel<<<dim3(1024), 256, 0, stream>>>(qb, kb, vT, opart, mlpart);
  combine_kernel<<<dim3(512), 256, 0, stream>>>(opart, mlpart, attn);
  gemm_bt_kernel<false><<<dim3(256), 256, 0, stream>>>(attn, WoutT, d_out, 4096, 1024, 1024, 8);
}

// Round 13
// 163.763 us; speedup vs baseline: 1.0320x; 1.0320x over previous
//
#include <hip/hip_runtime.h>
#include <hip/hip_bf16.h>
#include <stdint.h>
#include <math.h>

using bf16x8 = __attribute__((ext_vector_type(8))) short;
using bf16x4 = __attribute__((ext_vector_type(4))) short;
using f32x4  = __attribute__((ext_vector_type(4))) float;

#define DEV static __device__ __forceinline__

// SESSION LEDGER:
//  - r6/7: v_cvt_pk_bf16_f32 INLINE ASM => NaN. BANNED. packbf (compiler) green.
//  - r4/r12: exp2-domain q-prescale (log2e/8) => absmax 5.859e-3 BOTH times
//    (identical value; deterministic +2e-3). BANNED. q prescale must stay
//    EXACT POW2 (0.125) + __expf.
//  - r8 Q-split / r11 KV-split: partition-invariant ~80us; serial-chain-bound.
//    512-block / 128-q-row form is the keeper.
//  - r10: BK=64 swizzled-glds GEMM green, bit-identical. r5 NaN remains
//    unexplained (flake?); if an unexplained NaN recurs: revert GEMM to BK=32.
//  - r13 (this): keep tree-sum (reassociation) + exact-skip rescale
//    (bit-exact); numerics otherwise = r10 green.

DEV float bf2f(short s) {
  union { unsigned u; float f; } v; v.u = ((unsigned)(unsigned short)s) << 16; return v.f;
}
DEV short f2bf(float f) {
  union { float ff; unsigned u; } v; v.ff = f;
  unsigned r = v.u + 0x7fffu + ((v.u >> 16) & 1u);
  return (short)(r >> 16);
}
DEV unsigned packbf(float a, float b) {  // lo16 = RNE(a), hi16 = RNE(b)
  __hip_bfloat162 h = __float22bfloat162_rn(make_float2(a, b));
  union { __hip_bfloat162 h2; unsigned u; } v; v.h2 = h; return v.u;
}

DEV f32x4 mfma16x16x32(bf16x8 a, bf16x8 b, f32x4 c) {
  return __builtin_amdgcn_mfma_f32_16x16x32_bf16(a, b, c, 0, 0, 0);
}

DEV void glds16(const void* g, void* l) {
  __builtin_amdgcn_global_load_lds(
      (__attribute__((address_space(1))) void*)(uintptr_t)(g),
      (__attribute__((address_space(3))) void*)(l), 16, 0, 0);
}

#define B_   2
#define N_   2048
#define DIM_ 1024
#define H_   16
#define DH_  64
#define BH_  (B_ * H_)
#define BN_  (B_ * N_)

// ---------------------------------------------------------------------------
// 1) cos/sin table: cs[(n*32+j)*2] = cos(n * 10000^(-2j/64)), +1 = sin
// ---------------------------------------------------------------------------
__global__ void cs_kernel(float* __restrict__ cs) {
  int tid = blockIdx.x * blockDim.x + threadIdx.x;   // 65536 = 2048 * 32
  int n = tid >> 5, j = tid & 31;
  float inv = powf(10000.0f, -(float)(2 * j) / 64.0f);
  float ang = (float)n * inv;
  cs[2 * tid]     = cosf(ang);
  cs[2 * tid + 1] = sinf(ang);
}

// ---------------------------------------------------------------------------
// 2) fp32 -> bf16 elementwise (for x)
// ---------------------------------------------------------------------------
__global__ __launch_bounds__(256) void conv_kernel(const float* __restrict__ src,
                                                   short* __restrict__ dst) {
  int i = (blockIdx.x * 256 + threadIdx.x) * 8;
  float4 a = *(const float4*)(src + i);
  float4 b = *(const float4*)(src + i + 4);
  bf16x8 o;
  o[0] = f2bf(a.x); o[1] = f2bf(a.y); o[2] = f2bf(a.z); o[3] = f2bf(a.w);
  o[4] = f2bf(b.x); o[5] = f2bf(b.y); o[6] = f2bf(b.z); o[7] = f2bf(b.w);
  *(bf16x8*)(dst + i) = o;
}

// ---------------------------------------------------------------------------
// 3) transpose fp32 [R][C] -> bf16 [C][R]  (64x64 LDS tiles)
// ---------------------------------------------------------------------------
__global__ __launch_bounds__(256) void transw_kernel(const float* __restrict__ src,
                                                     short* __restrict__ dst,
                                                     int R, int C) {
  __shared__ unsigned short lds[64 * 65];
  const int t = threadIdx.x;
  const int cb = blockIdx.x * 64, rb = blockIdx.y * 64;
  #pragma unroll
  for (int pass = 0; pass < 4; ++pass) {
    int r  = pass * 16 + (t >> 4);
    int cc = (t & 15) * 4;
    float4 v = *(const float4*)(src + (size_t)(rb + r) * C + cb + cc);
    lds[(cc + 0) * 65 + r] = (unsigned short)f2bf(v.x);
    lds[(cc + 1) * 65 + r] = (unsigned short)f2bf(v.y);
    lds[(cc + 2) * 65 + r] = (unsigned short)f2bf(v.z);
    lds[(cc + 3) * 65 + r] = (unsigned short)f2bf(v.w);
  }
  __syncthreads();
  const int cl = t >> 2, chunk = t & 3;
  bf16x8 o0, o1;
  #pragma unroll
  for (int j = 0; j < 8; ++j) {
    o0[j] = (short)lds[cl * 65 + chunk * 16 + j];
    o1[j] = (short)lds[cl * 65 + chunk * 16 + 8 + j];
  }
  size_t off = (size_t)(cb + cl) * R + rb + chunk * 16;
  *(bf16x8*)(dst + off)     = o0;
  *(bf16x8*)(dst + off + 8) = o1;
}

// ---------------------------------------------------------------------------
// 4) GEMM: C[M][N] = A[M][K] (bf16, row-major) @ BT[N][K]^T (bf16)
//    128x128 tile, BK=64, chunk-XOR swizzled glds source (r10-proven).
// ---------------------------------------------------------------------------
template <bool OUTBF16>
__global__ __launch_bounds__(256) void gemm_bt_kernel(const short* __restrict__ A,
                                                      const short* __restrict__ BT,
                                                      void* __restrict__ Cout,
                                                      int M, int N, int K, int gx) {
  __shared__ short As[128 * 64];
  __shared__ short Bs[128 * 64];
  const int nwg = gridDim.x;
  const int bid = blockIdx.x;
  const int swz = (bid & 7) * (nwg >> 3) + (bid >> 3);  // bijective: nwg%8==0
  const int bx = swz % gx, by = swz / gx;
  const int t = threadIdx.x;
  const int lane = t & 63, w = t >> 6;
  const int c = lane & 15, g = lane >> 4;
  const int wm = w >> 1, wn = w & 1;
  const int mbase = by * 128, nbase = bx * 128;
  const short* Ab = A + (size_t)mbase * K;
  const short* Bb = BT + (size_t)nbase * K;
  f32x4 acc[4][4] = {};
  for (int kb2 = 0; kb2 < K; kb2 += 64) {
    #pragma unroll
    for (int i = 0; i < 4; ++i) {
      const int idx = i * 256 + t;             // 0..1023 chunk id
      const int row = idx >> 3, p = idx & 7;
      const int gc = ((p ^ (row & 7)) << 3);   // source chunk pre-swizzle
      glds16(Ab + (size_t)row * K + kb2 + gc, As + idx * 8);
      glds16(Bb + (size_t)row * K + kb2 + gc, Bs + idx * 8);
    }
    __syncthreads();
    bf16x8 af[4][2], bfr[4][2];
    #pragma unroll
    for (int mi = 0; mi < 4; ++mi) {
      const int r = wm * 64 + mi * 16 + c;
      #pragma unroll
      for (int kk = 0; kk < 2; ++kk)
        af[mi][kk] = *(const bf16x8*)&As[r * 64 + (((kk * 4 + g) ^ (r & 7)) << 3)];
    }
    #pragma unroll
    for (int ni = 0; ni < 4; ++ni) {
      const int r = wn * 64 + ni * 16 + c;
      #pragma unroll
      for (int kk = 0; kk < 2; ++kk)
        bfr[ni][kk] = *(const bf16x8*)&Bs[r * 64 + (((kk * 4 + g) ^ (r & 7)) << 3)];
    }
    #pragma unroll
    for (int kk = 0; kk < 2; ++kk)
      #pragma unroll
      for (int mi = 0; mi < 4; ++mi)
        #pragma unroll
        for (int ni = 0; ni < 4; ++ni)
          acc[mi][ni] = mfma16x16x32(af[mi][kk], bfr[ni][kk], acc[mi][ni]);
    __syncthreads();
  }
  #pragma unroll
  for (int mi = 0; mi < 4; ++mi) {
    const int row = mbase + wm * 64 + mi * 16 + g * 4;
    #pragma unroll
    for (int ni = 0; ni < 4; ++ni) {
      const int col = nbase + wn * 64 + ni * 16 + c;
      #pragma unroll
      for (int r = 0; r < 4; ++r) {
        if constexpr (OUTBF16)
          ((short*)Cout)[(size_t)(row + r) * N + col] = f2bf(acc[mi][ni][r]);
        else
          ((float*)Cout)[(size_t)(row + r) * N + col] = acc[mi][ni][r];
      }
    }
  }
}

// ---------------------------------------------------------------------------
// 5) RoPE on q,k: qkv bf16 [4096][3072] cols 0..2047 -> qb/kb [BH][N][64] bf16
//    q additionally scaled by 0.125 (EXACT pow2 — r4/r12 proved non-pow2
//    prescale deterministically costs +2e-3 absmax; BANNED)
// ---------------------------------------------------------------------------
__global__ __launch_bounds__(256) void ropeqk_kernel(const short* __restrict__ qkv,
                                                     const float* __restrict__ cs,
                                                     short* __restrict__ qb,
                                                     short* __restrict__ kb) {
  int tid = blockIdx.x * 256 + threadIdx.x;  // 2097152 threads, 4 elems each
  int e   = tid * 4;
  int bn  = e >> 11;
  int col = e & 2047;
  int i3  = col >> 10;
  int h   = (col >> 6) & 15;
  int d   = col & 63;
  int n   = bn & (N_ - 1);
  int b   = bn >> 11;
  bf16x4 v = *(const bf16x4*)(qkv + (size_t)bn * 3072 + col);
  float4 t4 = *(const float4*)(cs + ((size_t)n * 32 + (d >> 1)) * 2); // c0,s0,c1,s1
  float x0 = bf2f(v[0]), x1 = bf2f(v[1]), x2 = bf2f(v[2]), x3 = bf2f(v[3]);
  float r0 = x0 * t4.x - x1 * t4.y;
  float r1 = x0 * t4.y + x1 * t4.x;
  float r2 = x2 * t4.z - x3 * t4.w;
  float r3 = x2 * t4.w + x3 * t4.z;
  float sc = (i3 == 0) ? 0.125f : 1.0f;
  bf16x4 ov;
  ov[0] = f2bf(r0 * sc); ov[1] = f2bf(r1 * sc);
  ov[2] = f2bf(r2 * sc); ov[3] = f2bf(r3 * sc);
  short* dst = (i3 == 0) ? qb : kb;
  *(bf16x4*)(dst + (((size_t)(b * H_ + h) * N_ + n) * DH_ + d)) = ov;
}

// ---------------------------------------------------------------------------
// 6) V transpose: qkv cols 2048..3071 -> vT [BH][64][N] bf16
// ---------------------------------------------------------------------------
__global__ __launch_bounds__(256) void transv_kernel(const short* __restrict__ qkv,
                                                     short* __restrict__ vT) {
  __shared__ unsigned short lds[64 * 65];
  const int t = threadIdx.x;
  const int ntile = blockIdx.x;  // 0..31
  const int bh = blockIdx.y;     // 0..31
  const int b = bh >> 4, h = bh & 15;
  #pragma unroll
  for (int pass = 0; pass < 2; ++pass) {
    int rloc = pass * 32 + (t >> 3);
    int dc = t & 7;
    const short* src = qkv + (size_t)(b * N_ + ntile * 64 + rloc) * 3072 + 2048 + h * 64 + dc * 8;
    bf16x8 v = *(const bf16x8*)src;
    #pragma unroll
    for (int j = 0; j < 8; ++j) lds[(dc * 8 + j) * 65 + rloc] = (unsigned short)v[j];
  }
  __syncthreads();
  const int dl = t >> 2, chunk = t & 3;
  bf16x8 o0, o1;
  #pragma unroll
  for (int j = 0; j < 8; ++j) {
    o0[j] = (short)lds[dl * 65 + chunk * 16 + j];
    o1[j] = (short)lds[dl * 65 + chunk * 16 + 8 + j];
  }
  short* dst = vT + ((size_t)bh * 64 + dl) * N_ + ntile * 64 + chunk * 16;
  *(bf16x8*)dst       = o0;
  *(bf16x8*)(dst + 8) = o1;
}

// ---------------------------------------------------------------------------
// 7) Flash attention — r10 green numerics (0.125 prescale, __expf) + two
//    chain cuts: depth-5 tree sum (reassociation) and exact-skip rescale
//    (skip only when NO lane's max grew; skipped path is corr==1 for all
//    lanes => bit-identical to always-rescaling).
// ---------------------------------------------------------------------------
__global__ __launch_bounds__(256) void attn_kernel(const short* __restrict__ qb,
                                                   const short* __restrict__ kb,
                                                   const short* __restrict__ vT,
                                                   short* __restrict__ attn_out) {
  __shared__ short Kt[2][4096];   // 8 KB per buf: [row 0..63][chunk 0..7][8]
  __shared__ short Vt[2][4096];
  const int t = threadIdx.x;
  const int lane = t & 63, w = t >> 6;
  const int c = lane & 15, g = lane >> 4;
  const int bid = blockIdx.x;               // 512 blocks, 1D
  const int xcd = bid & 7, slot = bid >> 3; // slot 0..63
  const int bh = xcd + ((slot >> 4) << 3);  // 16 x-blocks of bh share an XCD
  const int xb = slot & 15;
  const int qbase = xb * 128 + w * 32;
  const short* kbase = kb + (size_t)bh * N_ * DH_;
  const short* vbase = vT + (size_t)bh * DH_ * N_;

  // staging map (per thread, 2 chunks per array): ch = j*256+t
  const int s_row0 = t >> 3,          s_p0 = t & 7;
  const int s_row1 = (256 + t) >> 3,  s_p1 = t & 7;   // rows 32..63
  const int s_dst0 = s_row0 * 64 + ((s_p0 ^ (s_row0 & 7)) << 3);
  const int s_dst1 = s_row1 * 64 + ((s_p1 ^ (s_row1 & 7)) << 3);

  // Q fragments held in registers for the whole kv loop; q pre-scaled 1/8
  bf16x8 qlo[2], qhi[2];
  #pragma unroll
  for (int qf = 0; qf < 2; ++qf) {
    const short* qp = qb + ((size_t)bh * N_ + qbase + qf * 16 + c) * DH_;
    qlo[qf] = *(const bf16x8*)(qp + g * 8);
    qhi[qf] = *(const bf16x8*)(qp + 32 + g * 8);
  }

  float M[2] = {-INFINITY, -INFINITY};
  float L[2] = {0.f, 0.f};
  f32x4 o[4][2] = {};
  bf16x8 kr0, kr1, vr0, vr1;

  // prologue: load tile 0 -> regs, write buf 0, barrier
  kr0 = *(const bf16x8*)(kbase + (size_t)s_row0 * DH_ + s_p0 * 8);
  kr1 = *(const bf16x8*)(kbase + (size_t)s_row1 * DH_ + s_p1 * 8);
  vr0 = *(const bf16x8*)(vbase + (size_t)s_row0 * N_ + s_p0 * 8);
  vr1 = *(const bf16x8*)(vbase + (size_t)s_row1 * N_ + s_p1 * 8);
  *(bf16x8*)(&Kt[0][s_dst0]) = kr0;
  *(bf16x8*)(&Kt[0][s_dst1]) = kr1;
  *(bf16x8*)(&Vt[0][s_dst0]) = vr0;
  *(bf16x8*)(&Vt[0][s_dst1]) = vr1;
  __syncthreads();

  for (int it = 0; it < 32; ++it) {
    const int cur = it & 1;
    const int pf_valid = (it + 1 < 32);
    if (pf_valid) {  // issue next-tile loads BEFORE compute (overlap)
      const int kv = (it + 1) * 64;
      kr0 = *(const bf16x8*)(kbase + (size_t)(kv + s_row0) * DH_ + s_p0 * 8);
      kr1 = *(const bf16x8*)(kbase + (size_t)(kv + s_row1) * DH_ + s_p1 * 8);
      vr0 = *(const bf16x8*)(vbase + (size_t)s_row0 * N_ + kv + s_p0 * 8);
      vr1 = *(const bf16x8*)(vbase + (size_t)s_row1 * N_ + kv + s_p1 * 8);
    }
    // --- QK^T: s lane holds S[q=qf*16+c][j=it*64+jt*16+g*4+r] ---
    f32x4 s[4][2] = {};
    __builtin_amdgcn_s_setprio(1);
    #pragma unroll
    for (int jt = 0; jt < 4; ++jt) {
      const int r_ = jt * 16 + c;
      const short* kt = &Kt[cur][r_ * 64];
      bf16x8 k0 = *(const bf16x8*)(kt + ((g ^ (r_ & 7)) << 3));
      bf16x8 k1 = *(const bf16x8*)(kt + (((g + 4) ^ (r_ & 7)) << 3));
      #pragma unroll
      for (int qf = 0; qf < 2; ++qf) {
        s[jt][qf] = mfma16x16x32(k0, qlo[qf], s[jt][qf]);
        s[jt][qf] = mfma16x16x32(k1, qhi[qf], s[jt][qf]);
      }
    }
    __builtin_amdgcn_s_setprio(0);
    // --- online softmax: exact-skip rescale + tree sum (expf, r10 numerics)
    bf16x8 pf[2][2];
    #pragma unroll
    for (int qf = 0; qf < 2; ++qf) {
      float m0 = fmaxf(fmaxf(s[0][qf][0], s[0][qf][1]), s[0][qf][2]);
      float m1 = fmaxf(fmaxf(s[0][qf][3], s[1][qf][0]), s[1][qf][1]);
      float m2 = fmaxf(fmaxf(s[1][qf][2], s[1][qf][3]), s[2][qf][0]);
      float m3 = fmaxf(fmaxf(s[2][qf][1], s[2][qf][2]), s[2][qf][3]);
      float m4 = fmaxf(fmaxf(s[3][qf][0], s[3][qf][1]), s[3][qf][2]);
      float mx = fmaxf(fmaxf(fmaxf(m0, m1), fmaxf(m2, m3)),
                       fmaxf(m4, s[3][qf][3]));
      mx = fmaxf(mx, __shfl_xor(mx, 16));
      mx = fmaxf(mx, __shfl_xor(mx, 32));
      if (__any(mx > M[qf])) {   // else corr==expf(0)==1 for all lanes: EXACT skip
        const float mnew = fmaxf(M[qf], mx);
        const float corr = __expf(M[qf] - mnew);  // exp(-inf)=0 first tile
        L[qf] *= corr;
        #pragma unroll
        for (int dt = 0; dt < 4; ++dt) o[dt][qf] *= corr;
        M[qf] = mnew;
      }
      #pragma unroll
      for (int jt = 0; jt < 4; ++jt)
        #pragma unroll
        for (int r = 0; r < 4; ++r)
          s[jt][qf][r] = __expf(s[jt][qf][r] - M[qf]);
      // depth-5 tree sum (was a 32-deep serial chain)
      float t0 = (s[0][qf][0] + s[0][qf][1]) + (s[0][qf][2] + s[0][qf][3]);
      float t1 = (s[1][qf][0] + s[1][qf][1]) + (s[1][qf][2] + s[1][qf][3]);
      float t2 = (s[2][qf][0] + s[2][qf][1]) + (s[2][qf][2] + s[2][qf][3]);
      float t3 = (s[3][qf][0] + s[3][qf][1]) + (s[3][qf][2] + s[3][qf][3]);
      float rs = (t0 + t1) + (t2 + t3);
      rs += __shfl_xor(rs, 16);
      rs += __shfl_xor(rs, 32);
      L[qf] += rs;
      union { unsigned u[4]; bf16x8 v; } P0, P1;
      P0.u[0] = packbf(s[0][qf][0], s[0][qf][1]);
      P0.u[1] = packbf(s[0][qf][2], s[0][qf][3]);
      P0.u[2] = packbf(s[1][qf][0], s[1][qf][1]);
      P0.u[3] = packbf(s[1][qf][2], s[1][qf][3]);
      P1.u[0] = packbf(s[2][qf][0], s[2][qf][1]);
      P1.u[1] = packbf(s[2][qf][2], s[2][qf][3]);
      P1.u[2] = packbf(s[3][qf][0], s[3][qf][1]);
      P1.u[3] = packbf(s[3][qf][2], s[3][qf][3]);
      pf[qf][0] = P0.v;
      pf[qf][1] = P1.v;
    }
    // --- PV: A = V^T rows d, slot map j = kf*32 + (s<4 ? g*4+s : 16+g*4+s-4)
    __builtin_amdgcn_s_setprio(1);
    #pragma unroll
    for (int dt = 0; dt < 4; ++dt) {
      const int d = dt * 16 + c;
      const short* vt = &Vt[cur][d * 64];
      const int dx = d & 7;
      #pragma unroll
      for (int kf = 0; kf < 2; ++kf) {
        const int e0 = kf * 32 + g * 4;
        const int e1 = e0 + 16;
        bf16x4 a0 = *(const bf16x4*)(vt + ((((e0 >> 3) ^ dx) << 3) | (e0 & 7)));
        bf16x4 a1 = *(const bf16x4*)(vt + ((((e1 >> 3) ^ dx) << 3) | (e1 & 7)));
        bf16x8 vf = __builtin_shufflevector(a0, a1, 0, 1, 2, 3, 4, 5, 6, 7);
        o[dt][0] = mfma16x16x32(vf, pf[0][kf], o[dt][0]);
        o[dt][1] = mfma16x16x32(vf, pf[1][kf], o[dt][1]);
      }
    }
    __builtin_amdgcn_s_setprio(0);
    // --- write-late: store prefetched regs into the idle buffer ---
    if (pf_valid) {
      *(bf16x8*)(&Kt[cur ^ 1][s_dst0]) = kr0;
      *(bf16x8*)(&Kt[cur ^ 1][s_dst1]) = kr1;
      *(bf16x8*)(&Vt[cur ^ 1][s_dst0]) = vr0;
      *(bf16x8*)(&Vt[cur ^ 1][s_dst1]) = vr1;
    }
    __syncthreads();
  }

  const int b = bh >> 4, h = bh & 15;
  #pragma unroll
  for (int qf = 0; qf < 2; ++qf) {
    const float inv = 1.0f / L[qf];
    short* op = attn_out + ((size_t)b * N_ + qbase + qf * 16 + c) * (H_ * DH_) + h * DH_;
    #pragma unroll
    for (int dt = 0; dt < 4; ++dt) {
      bf16x4 ov;
      #pragma unroll
      for (int r = 0; r < 4; ++r) ov[r] = f2bf(o[dt][qf][r] * inv);
      *(bf16x4*)(op + dt * 16 + g * 4) = ov;
    }
  }
}

// ---------------------------------------------------------------------------
extern "C" void kernel_launch(void* const* d_in, const int* in_sizes, int n_in,
                              void* d_out, int out_size, void* d_ws, size_t ws_size,
                              hipStream_t stream) {
  const float* x    = (const float*)d_in[0];
  const float* Wqkv = (const float*)d_in[1];
  const float* Wout = (const float*)d_in[2];
  char* ws = (char*)d_ws;
  // workspace layout (MiB offsets)
  short* xb    = (short*)(ws);                        // 8 MiB  [4096][1024]
  short* WqkvT = (short*)(ws + ((size_t)8 << 20));    // 6 MiB  [3072][1024]
  short* WoutT = (short*)(ws + ((size_t)14 << 20));   // 2 MiB  [1024][1024]
  short* qkv   = (short*)(ws + ((size_t)16 << 20));   // 24 MiB [4096][3072]
  short* qb    = (short*)(ws + ((size_t)40 << 20));   // 8 MiB  [32][2048][64]
  short* kb    = (short*)(ws + ((size_t)48 << 20));   // 8 MiB
  short* vT    = (short*)(ws + ((size_t)56 << 20));   // 8 MiB  [32][64][2048]
  short* attn  = (short*)(ws + ((size_t)64 << 20));   // 8 MiB  [4096][1024]
  float* cs    = (float*)(ws + ((size_t)72 << 20));   // 0.5 MiB [2048][32][2]

  cs_kernel<<<dim3(256), 256, 0, stream>>>(cs);
  conv_kernel<<<dim3(2048), 256, 0, stream>>>(x, xb);                       // x -> bf16
  transw_kernel<<<dim3(48, 16), 256, 0, stream>>>(Wqkv, WqkvT, 1024, 3072); // Wqkv^T
  transw_kernel<<<dim3(16, 16), 256, 0, stream>>>(Wout, WoutT, 1024, 1024); // Wout^T
  gemm_bt_kernel<true><<<dim3(768), 256, 0, stream>>>(xb, WqkvT, (void*)qkv, 4096, 3072, 1024, 24);
  ropeqk_kernel<<<dim3(8192), 256, 0, stream>>>(qkv, cs, qb, kb);
  transv_kernel<<<dim3(32, 32), 256, 0, stream>>>(qkv, vT);
  attn_kernel<<<dim3(512), 256, 0, stream>>>(qb, kb, vT, attn);
  gemm_bt_kernel<false><<<dim3(256), 256, 0, stream>>>(attn, WoutT, d_out, 4096, 1024, 1024, 8);
}

// Round 14
// 160.462 us; speedup vs baseline: 1.0532x; 1.0206x over previous
//
#include <hip/hip_runtime.h>
#include <hip/hip_bf16.h>
#include <stdint.h>
#include <math.h>

using bf16x8 = __attribute__((ext_vector_type(8))) short;
using bf16x4 = __attribute__((ext_vector_type(4))) short;
using f32x4  = __attribute__((ext_vector_type(4))) float;

#define DEV static __device__ __forceinline__

// SESSION LEDGER:
//  - r6/7: v_cvt_pk_bf16_f32 INLINE ASM => NaN. BANNED. packbf (compiler) green.
//  - r4/r12: exp2-domain q-prescale (log2e/8) => absmax 5.86e-3 both times.
//    BANNED. q prescale must stay EXACT POW2 (0.125) + __expf.
//  - r8/r11: attn partition-invariant ~80us (serial-chain-bound); r13 chain
//    cuts null. attn parked at r13 green form.
//  - r10: BK=64 swizzled-glds GEMM green. If unexplained NaN: revert to BK=32.
//  - r14 (this): fuse RoPE + V-transpose into GEMM1 epilogue via Wqkv column
//    permutation (phys p=32a+16s+c for logical d=2j+s, j=16a+c). Deletes
//    ropeqk/transv + qkv round-trip. Fallback: r13 source.

DEV float bf2f(short s) {
  union { unsigned u; float f; } v; v.u = ((unsigned)(unsigned short)s) << 16; return v.f;
}
DEV short f2bf(float f) {
  union { float ff; unsigned u; } v; v.ff = f;
  unsigned r = v.u + 0x7fffu + ((v.u >> 16) & 1u);
  return (short)(r >> 16);
}
DEV unsigned packbf(float a, float b) {  // lo16 = RNE(a), hi16 = RNE(b)
  __hip_bfloat162 h = __float22bfloat162_rn(make_float2(a, b));
  union { __hip_bfloat162 h2; unsigned u; } v; v.h2 = h; return v.u;
}

DEV f32x4 mfma16x16x32(bf16x8 a, bf16x8 b, f32x4 c) {
  return __builtin_amdgcn_mfma_f32_16x16x32_bf16(a, b, c, 0, 0, 0);
}

DEV void glds16(const void* g, void* l) {
  __builtin_amdgcn_global_load_lds(
      (__attribute__((address_space(1))) void*)(uintptr_t)(g),
      (__attribute__((address_space(3))) void*)(l), 16, 0, 0);
}

#define B_   2
#define N_   2048
#define DIM_ 1024
#define H_   16
#define DH_  64
#define BH_  (B_ * H_)
#define BN_  (B_ * N_)

// ---------------------------------------------------------------------------
// 1) cos/sin table: cs[(n*32+j)*2] = cos(n * 10000^(-2j/64)), +1 = sin
// ---------------------------------------------------------------------------
__global__ void cs_kernel(float* __restrict__ cs) {
  int tid = blockIdx.x * blockDim.x + threadIdx.x;   // 65536 = 2048 * 32
  int n = tid >> 5, j = tid & 31;
  float inv = powf(10000.0f, -(float)(2 * j) / 64.0f);
  float ang = (float)n * inv;
  cs[2 * tid]     = cosf(ang);
  cs[2 * tid + 1] = sinf(ang);
}

// ---------------------------------------------------------------------------
// 2) fp32 -> bf16 elementwise (for x)
// ---------------------------------------------------------------------------
__global__ __launch_bounds__(256) void conv_kernel(const float* __restrict__ src,
                                                   short* __restrict__ dst) {
  int i = (blockIdx.x * 256 + threadIdx.x) * 8;
  float4 a = *(const float4*)(src + i);
  float4 b = *(const float4*)(src + i + 4);
  bf16x8 o;
  o[0] = f2bf(a.x); o[1] = f2bf(a.y); o[2] = f2bf(a.z); o[3] = f2bf(a.w);
  o[4] = f2bf(b.x); o[5] = f2bf(b.y); o[6] = f2bf(b.z); o[7] = f2bf(b.w);
  *(bf16x8*)(dst + i) = o;
}

// ---------------------------------------------------------------------------
// 3) transpose fp32 [R][C] -> bf16 [C][R]  (64x64 LDS tiles)
//    PERM: for q/k thirds (cb < 2048) write row cb + pi(cl), where
//    pi(d): j=d>>1, s=d&1, a=j>>4, cj=j&15 -> 32a+16s+cj. This puts RoPE
//    pairs (2j,2j+1) into the SAME lane of the GEMM C-fragment (ni pairs).
// ---------------------------------------------------------------------------
template <bool PERM>
__global__ __launch_bounds__(256) void transw_kernel(const float* __restrict__ src,
                                                     short* __restrict__ dst,
                                                     int R, int C) {
  __shared__ unsigned short lds[64 * 65];
  const int t = threadIdx.x;
  const int cb = blockIdx.x * 64, rb = blockIdx.y * 64;
  #pragma unroll
  for (int pass = 0; pass < 4; ++pass) {
    int r  = pass * 16 + (t >> 4);
    int cc = (t & 15) * 4;
    float4 v = *(const float4*)(src + (size_t)(rb + r) * C + cb + cc);
    lds[(cc + 0) * 65 + r] = (unsigned short)f2bf(v.x);
    lds[(cc + 1) * 65 + r] = (unsigned short)f2bf(v.y);
    lds[(cc + 2) * 65 + r] = (unsigned short)f2bf(v.z);
    lds[(cc + 3) * 65 + r] = (unsigned short)f2bf(v.w);
  }
  __syncthreads();
  const int cl = t >> 2, chunk = t & 3;
  bf16x8 o0, o1;
  #pragma unroll
  for (int j = 0; j < 8; ++j) {
    o0[j] = (short)lds[cl * 65 + chunk * 16 + j];
    o1[j] = (short)lds[cl * 65 + chunk * 16 + 8 + j];
  }
  int ocl = cl;
  if (PERM && cb < 2048) {
    int j = cl >> 1, s2 = cl & 1;
    ocl = ((j >> 4) << 5) + (s2 << 4) + (j & 15);
  }
  size_t off = (size_t)(cb + ocl) * R + rb + chunk * 16;
  *(bf16x8*)(dst + off)     = o0;
  *(bf16x8*)(dst + off + 8) = o1;
}

// ---------------------------------------------------------------------------
// 4) GEMM: C = A @ BT^T. 128x128 tile, BK=64, chunk-XOR swizzled glds source
//    (r10-proven). MODE 0: f32 output. MODE 2: fused QKV epilogue —
//    q/k thirds: lane-local RoPE on f32 acc (perm'd W cols) -> qb/kb;
//    v third: transposed write -> vT. Bijective XCD swizzle (nwg%8==0).
// ---------------------------------------------------------------------------
template <int MODE>
__global__ __launch_bounds__(256) void gemm_bt_kernel(const short* __restrict__ A,
                                                      const short* __restrict__ BT,
                                                      float* __restrict__ Cout,
                                                      short* __restrict__ qb,
                                                      short* __restrict__ kb,
                                                      short* __restrict__ vT,
                                                      const float* __restrict__ cs,
                                                      int M, int N, int K, int gx) {
  __shared__ short As[128 * 64];
  __shared__ short Bs[128 * 64];
  const int nwg = gridDim.x;
  const int bid = blockIdx.x;
  const int swz = (bid & 7) * (nwg >> 3) + (bid >> 3);  // bijective: nwg%8==0
  const int bx = swz % gx, by = swz / gx;
  const int t = threadIdx.x;
  const int lane = t & 63, w = t >> 6;
  const int c = lane & 15, g = lane >> 4;
  const int wm = w >> 1, wn = w & 1;
  const int mbase = by * 128, nbase = bx * 128;
  const short* Ab = A + (size_t)mbase * K;
  const short* Bb = BT + (size_t)nbase * K;
  f32x4 acc[4][4] = {};
  for (int kb2 = 0; kb2 < K; kb2 += 64) {
    #pragma unroll
    for (int i = 0; i < 4; ++i) {
      const int idx = i * 256 + t;             // 0..1023 chunk id
      const int row = idx >> 3, p = idx & 7;
      const int gc = ((p ^ (row & 7)) << 3);   // source chunk pre-swizzle
      glds16(Ab + (size_t)row * K + kb2 + gc, As + idx * 8);
      glds16(Bb + (size_t)row * K + kb2 + gc, Bs + idx * 8);
    }
    __syncthreads();
    bf16x8 af[4][2], bfr[4][2];
    #pragma unroll
    for (int mi = 0; mi < 4; ++mi) {
      const int r = wm * 64 + mi * 16 + c;
      #pragma unroll
      for (int kk = 0; kk < 2; ++kk)
        af[mi][kk] = *(const bf16x8*)&As[r * 64 + (((kk * 4 + g) ^ (r & 7)) << 3)];
    }
    #pragma unroll
    for (int ni = 0; ni < 4; ++ni) {
      const int r = wn * 64 + ni * 16 + c;
      #pragma unroll
      for (int kk = 0; kk < 2; ++kk)
        bfr[ni][kk] = *(const bf16x8*)&Bs[r * 64 + (((kk * 4 + g) ^ (r & 7)) << 3)];
    }
    #pragma unroll
    for (int kk = 0; kk < 2; ++kk)
      #pragma unroll
      for (int mi = 0; mi < 4; ++mi)
        #pragma unroll
        for (int ni = 0; ni < 4; ++ni)
          acc[mi][ni] = mfma16x16x32(af[mi][kk], bfr[ni][kk], acc[mi][ni]);
    __syncthreads();
  }
  if constexpr (MODE == 0) {
    #pragma unroll
    for (int mi = 0; mi < 4; ++mi) {
      const int row = mbase + wm * 64 + mi * 16 + g * 4;
      #pragma unroll
      for (int ni = 0; ni < 4; ++ni) {
        const int col = nbase + wn * 64 + ni * 16 + c;
        #pragma unroll
        for (int r = 0; r < 4; ++r)
          Cout[(size_t)(row + r) * N + col] = acc[mi][ni][r];
      }
    }
  } else {
    const int col0 = nbase + wn * 64;     // head base; one head per warp
    const int i3 = col0 >> 10;            // 0=q, 1=k, 2=v
    const int h  = (col0 >> 6) & 15;
    if (i3 < 2) {
      // lane c holds logical d pairs: (2c,2c+1) at ni=0,1 ; (2c+32,2c+33) at ni=2,3
      short* dst0 = (i3 == 0) ? qb : kb;
      const float sc = (i3 == 0) ? 0.125f : 1.0f;
      #pragma unroll
      for (int mi = 0; mi < 4; ++mi) {
        const int row0 = mbase + wm * 64 + mi * 16 + g * 4;
        #pragma unroll
        for (int r = 0; r < 4; ++r) {
          const int row = row0 + r;
          const int n = row & 2047, b = row >> 11;
          short* dp = dst0 + ((size_t)(b * H_ + h) * N_ + n) * DH_;
          float2 cs0 = ((const float2*)cs)[n * 32 + c];
          float2 cs1 = ((const float2*)cs)[n * 32 + c + 16];
          float t1 = acc[mi][0][r], t2 = acc[mi][1][r];
          float t3 = acc[mi][2][r], t4 = acc[mi][3][r];
          unsigned u0 = packbf((t1 * cs0.x - t2 * cs0.y) * sc,
                               (t1 * cs0.y + t2 * cs0.x) * sc);
          unsigned u1 = packbf((t3 * cs1.x - t4 * cs1.y) * sc,
                               (t3 * cs1.y + t4 * cs1.x) * sc);
          *(unsigned*)(dp + 2 * c)      = u0;   // d = 2c, 2c+1
          *(unsigned*)(dp + 32 + 2 * c) = u1;   // d = 2c+32, 2c+33
        }
      }
    } else {
      // V: write transposed directly: vT[bh][d][n]
      #pragma unroll
      for (int mi = 0; mi < 4; ++mi) {
        const int row0 = mbase + wm * 64 + mi * 16 + g * 4;
        const int n0 = row0 & 2047, b = row0 >> 11;  // 4 rows same b
        const int bh = b * H_ + h;
        #pragma unroll
        for (int ni = 0; ni < 4; ++ni) {
          const int dd = ni * 16 + c;
          bf16x4 ov;
          #pragma unroll
          for (int r = 0; r < 4; ++r) ov[r] = f2bf(acc[mi][ni][r]);
          *(bf16x4*)(vT + ((size_t)bh * DH_ + dd) * N_ + n0) = ov;
        }
      }
    }
  }
}

// ---------------------------------------------------------------------------
// 7) Flash attention — r13 GREEN form, UNCHANGED. (512 blocks, 128 q-rows,
//    4 waves; reg-staged dbuf LDS; exact-skip rescale; tree sum; packbf.)
// ---------------------------------------------------------------------------
__global__ __launch_bounds__(256) void attn_kernel(const short* __restrict__ qb,
                                                   const short* __restrict__ kb,
                                                   const short* __restrict__ vT,
                                                   short* __restrict__ attn_out) {
  __shared__ short Kt[2][4096];   // 8 KB per buf: [row 0..63][chunk 0..7][8]
  __shared__ short Vt[2][4096];
  const int t = threadIdx.x;
  const int lane = t & 63, w = t >> 6;
  const int c = lane & 15, g = lane >> 4;
  const int bid = blockIdx.x;               // 512 blocks, 1D
  const int xcd = bid & 7, slot = bid >> 3; // slot 0..63
  const int bh = xcd + ((slot >> 4) << 3);  // 16 x-blocks of bh share an XCD
  const int xb = slot & 15;
  const int qbase = xb * 128 + w * 32;
  const short* kbase = kb + (size_t)bh * N_ * DH_;
  const short* vbase = vT + (size_t)bh * DH_ * N_;

  // staging map (per thread, 2 chunks per array): ch = j*256+t
  const int s_row0 = t >> 3,          s_p0 = t & 7;
  const int s_row1 = (256 + t) >> 3,  s_p1 = t & 7;   // rows 32..63
  const int s_dst0 = s_row0 * 64 + ((s_p0 ^ (s_row0 & 7)) << 3);
  const int s_dst1 = s_row1 * 64 + ((s_p1 ^ (s_row1 & 7)) << 3);

  // Q fragments held in registers for the whole kv loop; q pre-scaled 1/8
  bf16x8 qlo[2], qhi[2];
  #pragma unroll
  for (int qf = 0; qf < 2; ++qf) {
    const short* qp = qb + ((size_t)bh * N_ + qbase + qf * 16 + c) * DH_;
    qlo[qf] = *(const bf16x8*)(qp + g * 8);
    qhi[qf] = *(const bf16x8*)(qp + 32 + g * 8);
  }

  float M[2] = {-INFINITY, -INFINITY};
  float L[2] = {0.f, 0.f};
  f32x4 o[4][2] = {};
  bf16x8 kr0, kr1, vr0, vr1;

  // prologue: load tile 0 -> regs, write buf 0, barrier
  kr0 = *(const bf16x8*)(kbase + (size_t)s_row0 * DH_ + s_p0 * 8);
  kr1 = *(const bf16x8*)(kbase + (size_t)s_row1 * DH_ + s_p1 * 8);
  vr0 = *(const bf16x8*)(vbase + (size_t)s_row0 * N_ + s_p0 * 8);
  vr1 = *(const bf16x8*)(vbase + (size_t)s_row1 * N_ + s_p1 * 8);
  *(bf16x8*)(&Kt[0][s_dst0]) = kr0;
  *(bf16x8*)(&Kt[0][s_dst1]) = kr1;
  *(bf16x8*)(&Vt[0][s_dst0]) = vr0;
  *(bf16x8*)(&Vt[0][s_dst1]) = vr1;
  __syncthreads();

  for (int it = 0; it < 32; ++it) {
    const int cur = it & 1;
    const int pf_valid = (it + 1 < 32);
    if (pf_valid) {  // issue next-tile loads BEFORE compute (overlap)
      const int kv = (it + 1) * 64;
      kr0 = *(const bf16x8*)(kbase + (size_t)(kv + s_row0) * DH_ + s_p0 * 8);
      kr1 = *(const bf16x8*)(kbase + (size_t)(kv + s_row1) * DH_ + s_p1 * 8);
      vr0 = *(const bf16x8*)(vbase + (size_t)s_row0 * N_ + kv + s_p0 * 8);
      vr1 = *(const bf16x8*)(vbase + (size_t)s_row1 * N_ + kv + s_p1 * 8);
    }
    // --- QK^T: s lane holds S[q=qf*16+c][j=it*64+jt*16+g*4+r] ---
    f32x4 s[4][2] = {};
    __builtin_amdgcn_s_setprio(1);
    #pragma unroll
    for (int jt = 0; jt < 4; ++jt) {
      const int r_ = jt * 16 + c;
      const short* kt = &Kt[cur][r_ * 64];
      bf16x8 k0 = *(const bf16x8*)(kt + ((g ^ (r_ & 7)) << 3));
      bf16x8 k1 = *(const bf16x8*)(kt + (((g + 4) ^ (r_ & 7)) << 3));
      #pragma unroll
      for (int qf = 0; qf < 2; ++qf) {
        s[jt][qf] = mfma16x16x32(k0, qlo[qf], s[jt][qf]);
        s[jt][qf] = mfma16x16x32(k1, qhi[qf], s[jt][qf]);
      }
    }
    __builtin_amdgcn_s_setprio(0);
    // --- online softmax: exact-skip rescale + tree sum ---
    bf16x8 pf[2][2];
    #pragma unroll
    for (int qf = 0; qf < 2; ++qf) {
      float m0 = fmaxf(fmaxf(s[0][qf][0], s[0][qf][1]), s[0][qf][2]);
      float m1 = fmaxf(fmaxf(s[0][qf][3], s[1][qf][0]), s[1][qf][1]);
      float m2 = fmaxf(fmaxf(s[1][qf][2], s[1][qf][3]), s[2][qf][0]);
      float m3 = fmaxf(fmaxf(s[2][qf][1], s[2][qf][2]), s[2][qf][3]);
      float m4 = fmaxf(fmaxf(s[3][qf][0], s[3][qf][1]), s[3][qf][2]);
      float mx = fmaxf(fmaxf(fmaxf(m0, m1), fmaxf(m2, m3)),
                       fmaxf(m4, s[3][qf][3]));
      mx = fmaxf(mx, __shfl_xor(mx, 16));
      mx = fmaxf(mx, __shfl_xor(mx, 32));
      if (__any(mx > M[qf])) {   // else corr==expf(0)==1 for all lanes: EXACT skip
        const float mnew = fmaxf(M[qf], mx);
        const float corr = __expf(M[qf] - mnew);  // exp(-inf)=0 first tile
        L[qf] *= corr;
        #pragma unroll
        for (int dt = 0; dt < 4; ++dt) o[dt][qf] *= corr;
        M[qf] = mnew;
      }
      #pragma unroll
      for (int jt = 0; jt < 4; ++jt)
        #pragma unroll
        for (int r = 0; r < 4; ++r)
          s[jt][qf][r] = __expf(s[jt][qf][r] - M[qf]);
      float t0 = (s[0][qf][0] + s[0][qf][1]) + (s[0][qf][2] + s[0][qf][3]);
      float t1 = (s[1][qf][0] + s[1][qf][1]) + (s[1][qf][2] + s[1][qf][3]);
      float t2 = (s[2][qf][0] + s[2][qf][1]) + (s[2][qf][2] + s[2][qf][3]);
      float t3 = (s[3][qf][0] + s[3][qf][1]) + (s[3][qf][2] + s[3][qf][3]);
      float rs = (t0 + t1) + (t2 + t3);
      rs += __shfl_xor(rs, 16);
      rs += __shfl_xor(rs, 32);
      L[qf] += rs;
      union { unsigned u[4]; bf16x8 v; } P0, P1;
      P0.u[0] = packbf(s[0][qf][0], s[0][qf][1]);
      P0.u[1] = packbf(s[0][qf][2], s[0][qf][3]);
      P0.u[2] = packbf(s[1][qf][0], s[1][qf][1]);
      P0.u[3] = packbf(s[1][qf][2], s[1][qf][3]);
      P1.u[0] = packbf(s[2][qf][0], s[2][qf][1]);
      P1.u[1] = packbf(s[2][qf][2], s[2][qf][3]);
      P1.u[2] = packbf(s[3][qf][0], s[3][qf][1]);
      P1.u[3] = packbf(s[3][qf][2], s[3][qf][3]);
      pf[qf][0] = P0.v;
      pf[qf][1] = P1.v;
    }
    // --- PV: A = V^T rows d, slot map j = kf*32 + (s<4 ? g*4+s : 16+g*4+s-4)
    __builtin_amdgcn_s_setprio(1);
    #pragma unroll
    for (int dt = 0; dt < 4; ++dt) {
      const int d = dt * 16 + c;
      const short* vt = &Vt[cur][d * 64];
      const int dx = d & 7;
      #pragma unroll
      for (int kf = 0; kf < 2; ++kf) {
        const int e0 = kf * 32 + g * 4;
        const int e1 = e0 + 16;
        bf16x4 a0 = *(const bf16x4*)(vt + ((((e0 >> 3) ^ dx) << 3) | (e0 & 7)));
        bf16x4 a1 = *(const bf16x4*)(vt + ((((e1 >> 3) ^ dx) << 3) | (e1 & 7)));
        bf16x8 vf = __builtin_shufflevector(a0, a1, 0, 1, 2, 3, 4, 5, 6, 7);
        o[dt][0] = mfma16x16x32(vf, pf[0][kf], o[dt][0]);
        o[dt][1] = mfma16x16x32(vf, pf[1][kf], o[dt][1]);
      }
    }
    __builtin_amdgcn_s_setprio(0);
    // --- write-late: store prefetched regs into the idle buffer ---
    if (pf_valid) {
      *(bf16x8*)(&Kt[cur ^ 1][s_dst0]) = kr0;
      *(bf16x8*)(&Kt[cur ^ 1][s_dst1]) = kr1;
      *(bf16x8*)(&Vt[cur ^ 1][s_dst0]) = vr0;
      *(bf16x8*)(&Vt[cur ^ 1][s_dst1]) = vr1;
    }
    __syncthreads();
  }

  const int b = bh >> 4, h = bh & 15;
  #pragma unroll
  for (int qf = 0; qf < 2; ++qf) {
    const float inv = 1.0f / L[qf];
    short* op = attn_out + ((size_t)b * N_ + qbase + qf * 16 + c) * (H_ * DH_) + h * DH_;
    #pragma unroll
    for (int dt = 0; dt < 4; ++dt) {
      bf16x4 ov;
      #pragma unroll
      for (int r = 0; r < 4; ++r) ov[r] = f2bf(o[dt][qf][r] * inv);
      *(bf16x4*)(op + dt * 16 + g * 4) = ov;
    }
  }
}

// ---------------------------------------------------------------------------
extern "C" void kernel_launch(void* const* d_in, const int* in_sizes, int n_in,
                              void* d_out, int out_size, void* d_ws, size_t ws_size,
                              hipStream_t stream) {
  const float* x    = (const float*)d_in[0];
  const float* Wqkv = (const float*)d_in[1];
  const float* Wout = (const float*)d_in[2];
  char* ws = (char*)d_ws;
  // workspace layout (MiB offsets)
  short* xb    = (short*)(ws);                        // 8 MiB  [4096][1024]
  short* WqkvT = (short*)(ws + ((size_t)8 << 20));    // 6 MiB  [3072][1024] (perm'd q/k cols)
  short* WoutT = (short*)(ws + ((size_t)14 << 20));   // 2 MiB  [1024][1024]
  short* qb    = (short*)(ws + ((size_t)40 << 20));   // 8 MiB  [32][2048][64]
  short* kb    = (short*)(ws + ((size_t)48 << 20));   // 8 MiB
  short* vT    = (short*)(ws + ((size_t)56 << 20));   // 8 MiB  [32][64][2048]
  short* attn  = (short*)(ws + ((size_t)64 << 20));   // 8 MiB  [4096][1024]
  float* cs    = (float*)(ws + ((size_t)72 << 20));   // 0.5 MiB [2048][32][2]

  cs_kernel<<<dim3(256), 256, 0, stream>>>(cs);
  conv_kernel<<<dim3(2048), 256, 0, stream>>>(x, xb);                              // x -> bf16
  transw_kernel<true><<<dim3(48, 16), 256, 0, stream>>>(Wqkv, WqkvT, 1024, 3072);  // Wqkv^T (perm)
  transw_kernel<false><<<dim3(16, 16), 256, 0, stream>>>(Wout, WoutT, 1024, 1024); // Wout^T
  // GEMM1 with fused RoPE + V-transpose epilogue (writes qb, kb, vT directly)
  gemm_bt_kernel<2><<<dim3(768), 256, 0, stream>>>(xb, WqkvT, nullptr, qb, kb, vT, cs,
                                                   4096, 3072, 1024, 24);
  attn_kernel<<<dim3(512), 256, 0, stream>>>(qb, kb, vT, attn);
  gemm_bt_kernel<0><<<dim3(256), 256, 0, stream>>>(attn, WoutT, (float*)d_out,
                                                   nullptr, nullptr, nullptr, nullptr,
                                                   4096, 1024, 1024, 8);
}